// Round 5
// baseline (96.043 us; speedup 1.0000x reference)
//
#include <hip/hip_runtime.h>

// Channel_mixing8: per-pixel (B*H*W = 32768) over C=64 channels:
//   attn[i,j] = softmax_i( v[i]*k[j] );  out[i] = sum_j attn[i,j] * q[j]
// Restructured: S_j = sum_i exp(v_i k_j);  out_i = sum_j (q_j / S_j) * exp(v_i k_j)
//
// R5 = R4 with the DPP ctrl as a template parameter (the builtin requires a
// compile-time constant; a function arg fails clang's check even when inlined).
//  - 16 lanes per pixel (ICH=4): 8192 waves = 8 waves/SIMD available.
//  - e[8][4] = 32 live regs -> ~75 total, launch_bounds(256,6) (85-reg cap).
//  - 16-lane reduction entirely in DPP: xor1 (quad 0xB1), xor2 (quad 0x4E),
//    i^7 (row_half_mirror 0x141), i^15 (row_mirror 0x140). Valid butterfly:
//    each stage's swap distance lies outside the span already summed
//    ({0..3} -> +7 covers {0..7} -> +15 covers {0..15}). No LDS in j-loop.

constexpr int C    = 64;
constexpr int HW   = 128 * 128;          // 16384 = 1<<14
constexpr int NPIX = 2 * HW;             // 32768
constexpr int ICH  = 4;                  // i-channels per lane (C / 16)
constexpr int JT   = 8;                  // j-tile
constexpr int PXB  = 16;                 // pixels per block (256 thr / 16 lanes)
constexpr int LSTR = 68;                 // LDS row stride (floats), 16B-aligned
#define LOG2E 1.4426950408889634f

template <int CTRL>
__device__ __forceinline__ float dpp_add(float x) {
  int xi = __builtin_bit_cast(int, x);
  int yi = __builtin_amdgcn_update_dpp(0, xi, CTRL, 0xF, 0xF, true);
  return x + __builtin_bit_cast(float, yi);
}

__global__ __launch_bounds__(256, 6) void channel_mixing_kernel(
    const float* __restrict__ q,    // x
    const float* __restrict__ kk,   // y
    const float* __restrict__ v,    // z
    float* __restrict__ out) {
  __shared__ __align__(16) float lds_k[PXB * LSTR];
  __shared__ __align__(16) float lds_q[PXB * LSTR];

  const int t        = threadIdx.x;
  const int pixblock = blockIdx.x * PXB;
  // [b,c,h,w]: elem(b,c,phw) = (b<<20) + (c<<14) + phw; blocks never straddle b
  const int gbase = ((pixblock >> 14) << 20) | (pixblock & (HW - 1));

  // ---- stage k,q: 16 px x 64 j, coalesced (16 consecutive px per j) ----
#pragma unroll
  for (int rep = 0; rep < 4; ++rep) {
    const int idx = rep * 256 + t;        // 0..1023
    const int j   = idx >> 4;             // 0..63
    const int pxs = idx & 15;
    lds_k[pxs * LSTR + j] = kk[gbase + (j << 14) + pxs];
    lds_q[pxs * LSTR + j] = q [gbase + (j << 14) + pxs];
  }

  const int lane = t & 63;
  const int p    = lane >> 4;                  // pixel-in-wave [0,4)
  const int ig   = lane & 15;                  // i-group [0,16)
  const int px   = (t >> 6) * 4 + p;           // pixel-in-block [0,16)
  const int base  = gbase + px;
  const int cbase = base + (ig << 16);         // c = ig*4

  // my 4 v-channels, pre-scaled so exp(x) = exp2(x*log2e)
  float vv[ICH];
#pragma unroll
  for (int ii = 0; ii < ICH; ++ii)
    vv[ii] = v[cbase + (ii << 14)] * LOG2E;

  float acc[ICH];
#pragma unroll
  for (int ii = 0; ii < ICH; ++ii) acc[ii] = 0.0f;

  __syncthreads();

  const float* lkp = &lds_k[px * LSTR];
  const float* lqp = &lds_q[px * LSTR];

#pragma unroll 1
  for (int jt = 0; jt < C / JT; ++jt) {
    float kx[JT], qx[JT];
    *(float4*)&kx[0] = *(const float4*)&lkp[jt * JT];      // ds_read_b128
    *(float4*)&kx[4] = *(const float4*)&lkp[jt * JT + 4];
    *(float4*)&qx[0] = *(const float4*)&lqp[jt * JT];
    *(float4*)&qx[4] = *(const float4*)&lqp[jt * JT + 4];

    // 32 independent exps: trans-pipe ILP
    float e[JT][ICH];
#pragma unroll
    for (int jj = 0; jj < JT; ++jj)
#pragma unroll
      for (int ii = 0; ii < ICH; ++ii)
        e[jj][ii] = __builtin_amdgcn_exp2f(vv[ii] * kx[jj]);

    // 8 batched S-reductions over the 16-lane pixel group, all DPP
    float S[JT];
#pragma unroll
    for (int jj = 0; jj < JT; ++jj)
      S[jj] = (e[jj][0] + e[jj][1]) + (e[jj][2] + e[jj][3]);
#pragma unroll
    for (int jj = 0; jj < JT; ++jj) S[jj] = dpp_add<0xB1>(S[jj]);   // xor1
#pragma unroll
    for (int jj = 0; jj < JT; ++jj) S[jj] = dpp_add<0x4E>(S[jj]);   // xor2
#pragma unroll
    for (int jj = 0; jj < JT; ++jj) S[jj] = dpp_add<0x141>(S[jj]);  // i^7
#pragma unroll
    for (int jj = 0; jj < JT; ++jj) S[jj] = dpp_add<0x140>(S[jj]);  // i^15

#pragma unroll
    for (int jj = 0; jj < JT; ++jj) {
      const float w = qx[jj] * __builtin_amdgcn_rcpf(S[jj]);
#pragma unroll
      for (int ii = 0; ii < ICH; ++ii) acc[ii] += w * e[jj][ii];
    }
  }

#pragma unroll
  for (int ii = 0; ii < ICH; ++ii)
    out[cbase + (ii << 14)] = acc[ii];
}

extern "C" void kernel_launch(void* const* d_in, const int* in_sizes, int n_in,
                              void* d_out, int out_size, void* d_ws, size_t ws_size,
                              hipStream_t stream) {
  const float* q  = (const float*)d_in[0];  // x
  const float* kk = (const float*)d_in[1];  // y
  const float* v  = (const float*)d_in[2];  // z
  float* out = (float*)d_out;

  dim3 grid(NPIX / PXB);   // 2048 blocks x 256 threads, 16 px per block
  dim3 block(256);
  channel_mixing_kernel<<<grid, block, 0, stream>>>(q, kk, v, out);
}

// Round 6
// 89.636 us; speedup vs baseline: 1.0715x; 1.0715x over previous
//
#include <hip/hip_runtime.h>

// Channel_mixing8: per-pixel (B*H*W = 32768) over C=64 channels:
//   attn[i,j] = softmax_i( v[i]*k[j] );  out[i] = sum_j attn[i,j] * q[j]
// Restructured: S_j = sum_i exp(v_i k_j);  out_i = sum_j (q_j / S_j) * exp(v_i k_j)
//
// R6: R3 (4 waves/SIMD) == R5 (8 waves/SIMD) == ~37us -> NOT occupancy/latency
// bound; issue-bound on VALU+TRANS with v_exp_f32 costlier than modeled.
// Cut issue count: 3-stage DPP (8 lanes/px), float2-packed VALU (v_pk_* ),
// JT=4 tiles with register prefetch of next tile's k/q, coalesced staging.

constexpr int C    = 64;
constexpr int HW   = 128 * 128;          // 16384 = 1<<14
constexpr int NPIX = 2 * HW;             // 32768
constexpr int JT   = 4;                  // j-tile
constexpr int PXB  = 32;                 // pixels per block
constexpr int LSTR = 68;                 // LDS row stride (floats); 272B, 16B-aligned
#define LOG2E 1.4426950408889634f

template <int CTRL>
__device__ __forceinline__ float dpp_add(float x) {
  int xi = __builtin_bit_cast(int, x);
  int yi = __builtin_amdgcn_update_dpp(0, xi, CTRL, 0xF, 0xF, true);
  return x + __builtin_bit_cast(float, yi);
}

__global__ __launch_bounds__(256, 4) void channel_mixing_kernel(
    const float* __restrict__ q,    // x
    const float* __restrict__ kk,   // y
    const float* __restrict__ v,    // z
    float* __restrict__ out) {
  __shared__ __align__(16) float lds_k[PXB * LSTR];
  __shared__ __align__(16) float lds_q[PXB * LSTR];

  const int t        = threadIdx.x;
  const int pixblock = blockIdx.x * PXB;
  // [b,c,h,w]: elem(b,c,phw) = (b<<20) + (c<<14) + phw; blocks never straddle b
  const int gbase = ((pixblock >> 14) << 20) | (pixblock & (HW - 1));

  const int lane = t & 63;
  const int p    = lane >> 3;                  // pixel-in-wave [0,8)
  const int ig   = lane & 7;                   // i-group [0,8): owns channels ig*8..+7
  const int px   = (t >> 6) * 8 + p;           // pixel-in-block [0,32)
  const int base  = gbase + px;
  const int cbase = base + (ig << 17);         // c = ig*8

  // v loads first (long-latency, consumed after the barrier); packed pairs
  float2 vv2[4];
#pragma unroll
  for (int n = 0; n < 4; ++n) {
    float a = v[cbase + ((2 * n) << 14)];
    float b = v[cbase + ((2 * n + 1) << 14)];
    vv2[n] = make_float2(a * LOG2E, b * LOG2E);
  }

  // ---- stage k,q: 64 j x 32 px, fully coalesced float4 loads along px ----
#pragma unroll
  for (int rep = 0; rep < 2; ++rep) {
    const int s  = rep * 256 + t;     // float4-slot [0,512)
    const int j  = s >> 3;            // [0,64)
    const int pg = (s & 7) * 4;       // px group start
    float4 k4 = *(const float4*)&kk[gbase + (j << 14) + pg];
    float4 q4 = *(const float4*)&q [gbase + (j << 14) + pg];
    lds_k[(pg + 0) * LSTR + j] = k4.x;  lds_q[(pg + 0) * LSTR + j] = q4.x;
    lds_k[(pg + 1) * LSTR + j] = k4.y;  lds_q[(pg + 1) * LSTR + j] = q4.y;
    lds_k[(pg + 2) * LSTR + j] = k4.z;  lds_q[(pg + 2) * LSTR + j] = q4.z;
    lds_k[(pg + 3) * LSTR + j] = k4.w;  lds_q[(pg + 3) * LSTR + j] = q4.w;
  }

  float2 acc2[4];
#pragma unroll
  for (int n = 0; n < 4; ++n) acc2[n] = make_float2(0.0f, 0.0f);

  __syncthreads();

  const float4* lkp4 = (const float4*)&lds_k[px * LSTR];
  const float4* lqp4 = (const float4*)&lds_q[px * LSTR];

  float4 kx4 = lkp4[0];
  float4 qx4 = lqp4[0];

#pragma unroll 1
  for (int jt = 0; jt < C / JT; ++jt) {
    // prefetch next tile's k,q (consumed next iteration -> latency hidden)
    const int nxt = (jt < C / JT - 1) ? jt + 1 : jt;
    float4 kxn = lkp4[nxt];
    float4 qxn = lqp4[nxt];

    const float kx[JT] = {kx4.x, kx4.y, kx4.z, kx4.w};
    const float qx[JT] = {qx4.x, qx4.y, qx4.z, qx4.w};

    // 32 independent exps (trans ILP); muls packed (v_pk_mul_f32)
    float2 e2[JT][4];
#pragma unroll
    for (int jj = 0; jj < JT; ++jj)
#pragma unroll
      for (int n = 0; n < 4; ++n) {
        float mx = vv2[n].x * kx[jj];
        float my = vv2[n].y * kx[jj];
        e2[jj][n] = make_float2(__builtin_amdgcn_exp2f(mx),
                                __builtin_amdgcn_exp2f(my));
      }

    // batched column sums: packed tree + 3-stage DPP over the 8-lane group
    float S[JT];
#pragma unroll
    for (int jj = 0; jj < JT; ++jj) {
      float2 s2 = make_float2((e2[jj][0].x + e2[jj][1].x) + (e2[jj][2].x + e2[jj][3].x),
                              (e2[jj][0].y + e2[jj][1].y) + (e2[jj][2].y + e2[jj][3].y));
      S[jj] = s2.x + s2.y;
    }
#pragma unroll
    for (int jj = 0; jj < JT; ++jj) S[jj] = dpp_add<0xB1>(S[jj]);   // xor1
#pragma unroll
    for (int jj = 0; jj < JT; ++jj) S[jj] = dpp_add<0x4E>(S[jj]);   // xor2
#pragma unroll
    for (int jj = 0; jj < JT; ++jj) S[jj] = dpp_add<0x141>(S[jj]);  // i^7 in 8-group

#pragma unroll
    for (int jj = 0; jj < JT; ++jj) {
      const float w = qx[jj] * __builtin_amdgcn_rcpf(S[jj]);
#pragma unroll
      for (int n = 0; n < 4; ++n) {                 // v_pk_fma_f32
        acc2[n].x += w * e2[jj][n].x;
        acc2[n].y += w * e2[jj][n].y;
      }
    }

    kx4 = kxn;
    qx4 = qxn;
  }

#pragma unroll
  for (int n = 0; n < 4; ++n) {
    out[cbase + ((2 * n) << 14)]     = acc2[n].x;
    out[cbase + ((2 * n + 1) << 14)] = acc2[n].y;
  }
}

extern "C" void kernel_launch(void* const* d_in, const int* in_sizes, int n_in,
                              void* d_out, int out_size, void* d_ws, size_t ws_size,
                              hipStream_t stream) {
  const float* q  = (const float*)d_in[0];  // x
  const float* kk = (const float*)d_in[1];  // y
  const float* v  = (const float*)d_in[2];  // z
  float* out = (float*)d_out;

  dim3 grid(NPIX / PXB);   // 1024 blocks x 256 threads, 32 px per block
  dim3 block(256);
  channel_mixing_kernel<<<grid, block, 0, stream>>>(q, kk, v, out);
}